// Round 5
// baseline (398.420 us; speedup 1.0000x reference)
//
#include <hip/hip_runtime.h>

typedef __bf16 bf16x8 __attribute__((ext_vector_type(8)));
typedef float f32x4 __attribute__((ext_vector_type(4)));

// ---------------- sizes ----------------
// B=8, LAT=512, CIN=F=256, Hin=Win=64, H=W=128, K=3
// ws layout (bytes):
//   xu_p NHWC bf16 [8][130][130][256] : off 0          size 69222400
//   y1_p NHWC bf16 [8][130][130][256] : off 69222400   size 69222400
//   wm   bf16 [8][256][9][256]        : off 138444800  size 9437184   (reused)
//   sbuf f32 [2][8][256]              : off 147881984  size 16384

#define GLDS(gsrc, ldst) __builtin_amdgcn_global_load_lds( \
    (const __attribute__((address_space(1))) unsigned int*)(gsrc), \
    (__attribute__((address_space(3))) unsigned int*)(ldst), 16, 0, 0)

#define MFMA(a, b, c) __builtin_amdgcn_mfma_f32_16x16x32_bf16((a), (b), (c), 0, 0, 0)

// ---------------- styles ----------------
__global__ void style_kernel(const float* __restrict__ istyle,
                             const float* __restrict__ ws1, const float* __restrict__ bs1,
                             const float* __restrict__ ws2, const float* __restrict__ bs2,
                             float* __restrict__ sbuf) {
    int b = blockIdx.x;
    int which = blockIdx.y;
    int c = threadIdx.x;
    const float* ws = which ? ws2 : ws1;
    const float* bs = which ? bs2 : bs1;
    __shared__ float st[512];
    for (int i = threadIdx.x; i < 512; i += 256) st[i] = istyle[b * 512 + i];
    __syncthreads();
    float acc = bs[c];
    const float* wr = ws + (size_t)c * 512;
    for (int l = 0; l < 512; ++l) acc += st[l] * wr[l];
    sbuf[((size_t)which * 8 + b) * 256 + c] = acc;
}

// ---------------- modulate + demodulate -> bf16 [b][o][tap][c] ----------------
// One wave per (b,o): lane covers 4 channels x 9 taps; shfl-xor wave reduce.
__global__ void modw_kernel(const float* __restrict__ w, const float* __restrict__ s,
                            __bf16* __restrict__ wm) {
    int wv = threadIdx.x >> 6, lane = threadIdx.x & 63;
    int idx = blockIdx.x * 4 + wv;      // 0..2047
    int b = idx >> 8, o = idx & 255;
    int c0 = lane * 4;
    const float* wr = w + ((size_t)o * 256 + c0) * 9;
    const float* sb = s + (size_t)b * 256 + c0;
    float v[36];
    float ss = 0.f;
#pragma unroll
    for (int cc = 0; cc < 4; ++cc) {
        float sm = sb[cc] + 1.0f;
#pragma unroll
        for (int t = 0; t < 9; ++t) {
            float x = wr[cc * 9 + t] * sm;
            v[cc * 9 + t] = x;
            ss += x * x;
        }
    }
#pragma unroll
    for (int off = 32; off > 0; off >>= 1) ss += __shfl_xor(ss, off);
    float d = rsqrtf(ss + 1e-8f);
    __bf16* wp = wm + ((size_t)(b * 256 + o) * 9) * 256 + c0;
#pragma unroll
    for (int t = 0; t < 9; ++t) {
        union { __bf16 h[4]; uint2 u; } pk;
#pragma unroll
        for (int cc = 0; cc < 4; ++cc) pk.h[cc] = (__bf16)(v[cc * 9 + t] * d);
        *(uint2*)(wp + (size_t)t * 256) = pk.u;
    }
}

// ---------------- zero the 1-pixel border ----------------
__global__ void zeropad_kernel(__bf16* __restrict__ xu, __bf16* __restrict__ y1) {
    int p0 = blockIdx.x * 8;
    int b  = blockIdx.y;
    __bf16* buf = blockIdx.z ? y1 : xu;
    int p = p0 + (threadIdx.x >> 5);
    if (p >= 516) return;
    int chunk = threadIdx.x & 31;
    int y, x;
    if (p < 130)      { y = 0;           x = p; }
    else if (p < 260) { y = 129;         x = p - 130; }
    else if (p < 388) { y = p - 260 + 1; x = 0; }
    else              { y = p - 388 + 1; x = 129; }
    uint4 z = make_uint4(0, 0, 0, 0);
    *(uint4*)(buf + (((size_t)b * 130 + y) * 130 + x) * 256 + chunk * 8) = z;
}

// ---------------- bilinear 2x upsample NCHW f32 -> padded NHWC bf16 ----------------
__global__ void upsample_kernel(const float* __restrict__ x, __bf16* __restrict__ xu) {
    int ct = blockIdx.x;
    int y  = blockIdx.y;
    int b  = blockIdx.z;
    int c0 = ct * 32;
    __shared__ float up[32 * 132];
    int tid = threadIdx.x;

    int j = y >> 1;
    int y0, y1; float wy0, wy1;
    if (y & 1) { y0 = j; y1 = (j + 1 < 64) ? j + 1 : 63; wy0 = 0.75f; wy1 = 0.25f; }
    else       { y0 = (j - 1 >= 0) ? j - 1 : 0; y1 = j; wy0 = 0.25f; wy1 = 0.75f; }

    int c  = tid >> 3;
    int xs = (tid & 7) * 16;
    const float* row0 = x + ((size_t)(b * 256 + c0 + c) * 64 + y0) * 64;
    const float* row1 = x + ((size_t)(b * 256 + c0 + c) * 64 + y1) * 64;
#pragma unroll
    for (int k = 0; k < 16; ++k) {
        int xo = xs + k;
        int i = xo >> 1;
        int x0, x1; float wx0, wx1;
        if (xo & 1) { x0 = i; x1 = (i + 1 < 64) ? i + 1 : 63; wx0 = 0.75f; wx1 = 0.25f; }
        else        { x0 = (i - 1 >= 0) ? i - 1 : 0; x1 = i; wx0 = 0.25f; wx1 = 0.75f; }
        float v0 = wx0 * row0[x0] + wx1 * row0[x1];
        float v1 = wx0 * row1[x0] + wx1 * row1[x1];
        up[c * 132 + xo] = wy0 * v0 + wy1 * v1;
    }
    __syncthreads();
    int xo = tid >> 1, half = tid & 1;
    union { __bf16 v[8]; uint4 u; } pk;
#pragma unroll
    for (int g = 0; g < 2; ++g) {
#pragma unroll
        for (int i = 0; i < 8; ++i)
            pk.v[i] = (__bf16)up[(half * 16 + g * 8 + i) * 132 + xo];
        *(uint4*)(xu + (((size_t)(b * 130) + y + 1) * 130 + xo + 1) * 256 + c0 + half * 16 + g * 8) = pk.u;
    }
}

// ---------------- implicit-GEMM modulated conv, 128x128 tile, 64KB LDS ----------------
// Per block: batch b, ONE output row (128 px), half the out-channels (om).
// M=128, N=128, K=2304, BK=64 -> 36 K-tiles. 4 waves (2Mx2N), per-wave 64x64 out.
// LDS 64KB -> 2 blocks/CU: cross-block overlap hides per-tile latency (m114).
// Per tile: issue all 8 GLDS for t+1 at tile top (full-tile slack), 16 ds_reads,
// 32-MFMA cluster, vmcnt(0)+s_barrier at tile end only. XOR-chunk swizzle (0 conflicts).
// K-order c0-major/tap-minor keeps input rows L2-hot (R4 verified: FETCH 44MB).
template <int PHASE>
__global__ __launch_bounds__(256, 2) void conv_kernel(
    const __bf16* __restrict__ in,    // padded NHWC [8][130][130][256]
    const __bf16* __restrict__ wmall, // [8][256][9][256]
    float* __restrict__ outf,
    __bf16* __restrict__ outb) {
    __shared__ __attribute__((aligned(128))) char smem[65536];
    __bf16* const sA = (__bf16*)smem;             // [2][128*64]
    __bf16* const sB = (__bf16*)(smem + 32768);   // [2][128*64]
    const int tid  = threadIdx.x;
    const int bid  = blockIdx.x;
    // XCD-bijective swizzle: 2048 blocks = 8 XCDs x 256; one batch per XCD.
    const int swz  = (bid & 7) * 256 + (bid >> 3);
    const int b    = swz >> 8;
    const int rem  = swz & 255;
    const int yrow = rem >> 1;
    const int om   = (rem & 1) * 128;
    const int lane = tid & 63;
    const int wv   = tid >> 6;          // 0..3
    const int wo   = (wv >> 1) * 64;    // wave M offset
    const int wn   = (wv & 1) * 64;     // wave N offset
    const int arow = lane & 15;
    const int cgb  = lane >> 4;         // 0..3
    const int lr   = lane >> 3;
    const int lc   = lane & 7;
    const int swz8 = (lc ^ lr) * 8;
    const __bf16* wm_b = wmall + (size_t)(b * 256 + om) * 2304;

    size_t aOff[4], bOff[4];
    int dst[4];
#pragma unroll
    for (int q = 0; q < 4; ++q) {
        int r = q * 32 + wv * 8 + lr;           // 0..127
        aOff[q] = (size_t)r * 2304 + swz8;
        bOff[q] = ((size_t)((b * 130 + yrow) * 130 + r)) * 256 + swz8;
        dst[q]  = (q * 32 + wv * 8) * 64;
    }

    f32x4 acc[4][4] = {};

    // prologue: stage tile 0 (tap 0, c0=0)
#pragma unroll
    for (int q = 0; q < 4; ++q) {
        GLDS(wm_b + aOff[q], sA + dst[q]);
        GLDS(in   + bOff[q], sB + dst[q]);
    }
    asm volatile("s_waitcnt vmcnt(0)" ::: "memory");
    __builtin_amdgcn_s_barrier();
    asm volatile("" ::: "memory");

    for (int t = 0; t < 36; ++t) {
        const __bf16* Ac = sA + (t & 1) * 8192;
        const __bf16* Bc = sB + (t & 1) * 8192;
        __bf16* An = sA + ((t + 1) & 1) * 8192;
        __bf16* Bn = sB + ((t + 1) & 1) * 8192;
        // issue next tile's staging at tile top: slack = whole tile body
        if (t < 35) {
            const int nt   = t + 1;
            const int ncb  = nt / 9;
            const int ntap = nt - 9 * ncb;
            const int nc0  = ncb * 64;
            const int nky  = ntap / 3, nkx = ntap - 3 * nky;
            const size_t boff_t = (size_t)((nky * 130 + nkx) * 256 + nc0);
            const size_t aoff_t = (size_t)(ntap * 256 + nc0);
#pragma unroll
            for (int q = 0; q < 4; ++q) {
                GLDS(wm_b + aOff[q] + aoff_t, An + dst[q]);
                GLDS(in   + bOff[q] + boff_t, Bn + dst[q]);
            }
        }
        bf16x8 bfr[4][2], af[4][2];
#pragma unroll
        for (int j = 0; j < 4; ++j) {
            int rb = wn + j * 16 + arow;
            const char* bp = (const char*)Bc + rb * 128;
            bfr[j][0] = *(const bf16x8*)(bp + ((cgb ^ (rb & 7)) * 16));
            bfr[j][1] = *(const bf16x8*)(bp + (((cgb + 4) ^ (rb & 7)) * 16));
        }
#pragma unroll
        for (int m = 0; m < 4; ++m) {
            int ra = wo + m * 16 + arow;
            const char* ap = (const char*)Ac + ra * 128;
            af[m][0] = *(const bf16x8*)(ap + ((cgb ^ (ra & 7)) * 16));
            af[m][1] = *(const bf16x8*)(ap + (((cgb + 4) ^ (ra & 7)) * 16));
        }
        __builtin_amdgcn_s_setprio(1);
#pragma unroll
        for (int m = 0; m < 4; ++m)
#pragma unroll
            for (int j = 0; j < 4; ++j) {
                acc[m][j] = MFMA(af[m][0], bfr[j][0], acc[m][j]);
                acc[m][j] = MFMA(af[m][1], bfr[j][1], acc[m][j]);
            }
        __builtin_amdgcn_s_setprio(0);
        asm volatile("s_waitcnt vmcnt(0)" ::: "memory");
        __builtin_amdgcn_s_barrier();
        asm volatile("" ::: "memory");
    }

    // pin all pending LDS reads / MFMAs before reusing smem (rule #18)
    __builtin_amdgcn_sched_barrier(0);
    __syncthreads();

    if (PHASE == 1) {
        // stage output tile [n=128 px][128 och -> 256B] into LDS, XOR-swizzled
        __bf16* const ot = (__bf16*)smem;
        const int cg = lane >> 4;
#pragma unroll
        for (int m = 0; m < 4; ++m)
#pragma unroll
            for (int j = 0; j < 4; ++j) {
                int n  = wn + j * 16 + arow;
                int ob = (wo + m * 16 + cg * 4) * 2;   // byte offset within 256B row
                union { __bf16 v[4]; uint2 u; } pk;
#pragma unroll
                for (int r = 0; r < 4; ++r) {
                    float v = acc[m][j][r];
                    pk.v[r] = (__bf16)((v > 0.f) ? v : 0.2f * v);
                }
                *(uint2*)((char*)ot + n * 256 + (ob ^ ((n & 7) << 4))) = pk.u;
            }
        __syncthreads();
        // flush: 4 px/iter, 16 lanes x 16B = contiguous 256B per pixel
        const int p4  = lane >> 4;
        const int c16 = lane & 15;
#pragma unroll
        for (int it = 0; it < 8; ++it) {
            int n = wv * 32 + it * 4 + p4;
            uint4 v = *(const uint4*)((const char*)ot + n * 256 + ((c16 * 16) ^ ((n & 7) << 4)));
            *(uint4*)(outb + (((size_t)(b * 130) + yrow + 1) * 130 + n + 1) * 256 + om + c16 * 8) = v;
        }
    } else {
        // NCHW f32: 16 lanes x 4B = contiguous 64B lines
#pragma unroll
        for (int m = 0; m < 4; ++m)
#pragma unroll
            for (int j = 0; j < 4; ++j) {
                int o_base = om + wo + m * 16 + (lane >> 4) * 4;
                int n      = wn + j * 16 + (lane & 15);
#pragma unroll
                for (int r = 0; r < 4; ++r) {
                    float v = acc[m][j][r];
                    v = (v > 0.f) ? v : 0.2f * v;
                    outf[((size_t)(b * 256 + o_base + r) * 128 + yrow) * 128 + n] = v;
                }
            }
    }
}

extern "C" void kernel_launch(void* const* d_in, const int* in_sizes, int n_in,
                              void* d_out, int out_size, void* d_ws, size_t ws_size,
                              hipStream_t stream) {
    const float* x      = (const float*)d_in[0];
    const float* istyle = (const float*)d_in[1];
    const float* ws1    = (const float*)d_in[2];
    const float* bs1    = (const float*)d_in[3];
    const float* w1     = (const float*)d_in[4];
    const float* ws2    = (const float*)d_in[5];
    const float* bs2    = (const float*)d_in[6];
    const float* w2     = (const float*)d_in[7];
    float* out = (float*)d_out;

    char* ws = (char*)d_ws;
    __bf16* xu_p = (__bf16*)(ws);
    __bf16* y1_p = (__bf16*)(ws + 69222400);
    __bf16* wm   = (__bf16*)(ws + 138444800);
    float*  sbuf = (float*)(ws + 147881984);

    style_kernel<<<dim3(8, 2), 256, 0, stream>>>(istyle, ws1, bs1, ws2, bs2, sbuf);
    zeropad_kernel<<<dim3(65, 8, 2), 256, 0, stream>>>(xu_p, y1_p);
    upsample_kernel<<<dim3(8, 128, 8), 256, 0, stream>>>(x, xu_p);
    modw_kernel<<<dim3(512), 256, 0, stream>>>(w1, sbuf, wm);
    conv_kernel<1><<<dim3(2048), 256, 0, stream>>>(xu_p, wm, nullptr, y1_p);
    modw_kernel<<<dim3(512), 256, 0, stream>>>(w2, sbuf + 2048, wm);
    conv_kernel<2><<<dim3(2048), 256, 0, stream>>>(y1_p, wm, out, nullptr);
}